// Round 4
// baseline (118.891 us; speedup 1.0000x reference)
//
#include <hip/hip_runtime.h>
#include <math.h>

#define GRID_D 362
#define NKEYS  10000
#define EPSV   1e-8f
#define MROWS  8
#define NTHR   512

__device__ __forceinline__ float rfl(float x) {
    return __int_as_float(__builtin_amdgcn_readfirstlane(__float_as_int(x)));
}

// ---------- fused prep (argmax/q/cells/bucket, 4 rows/block) + pack (kv -> 64B rows) ----------
__global__ __launch_bounds__(256) void prep_pack_kernel(
    const float* __restrict__ batch_x,
    const int*   __restrict__ batch_a,
    const float* __restrict__ keys,      // [3*10000, 6]
    const float* __restrict__ values,    // [3*10000, 7]
    int*   __restrict__ cnt,             // [4] zeroed
    int*   __restrict__ rowlist,         // [3*B]
    float* __restrict__ qout,            // [B*6]
    int*   __restrict__ cellout,         // [B*6]
    float* __restrict__ packed,          // [3*10000, 16]
    int B, int prep_blocks, int do_pack)
{
    if ((int)blockIdx.x >= prep_blocks) {
        // ---- pack: one thread per key-row ----
        const int i = (blockIdx.x - prep_blocks) * 256 + threadIdx.x;
        if (i >= 3 * NKEYS) return;
        const float* k = keys   + (size_t)i * 6;
        const float* v = values + (size_t)i * 7;
        const float k0 = k[0], k1 = k[1], k2 = k[2], k3 = k[3], k4 = k[4], k5 = k[5];
        const float nn = k0*k0 + k1*k1 + k2*k2 + k3*k3 + k4*k4 + k5*k5;
        const float invn = 1.f / (sqrtf(nn) + EPSV);
        float4* p = (float4*)(packed + (size_t)i * 16);
        p[0] = make_float4(k0*invn, k1*invn, k2*invn, k3*invn);
        p[1] = make_float4(k4*invn, k5*invn, v[0], v[1]);
        p[2] = make_float4(v[2], v[3], v[4], v[5]);
        p[3] = make_float4(v[6], 0.f, 0.f, 0.f);
        return;
    }

    // ---- prep: 4 rows/block, one wave each ----
    const int wid  = threadIdx.x >> 6;
    const int lane = threadIdx.x & 63;
    const int b    = blockIdx.x * 4 + wid;
    if (b >= B) return;
    const float* x = batch_x + (size_t)b * GRID_D;

    float bestv = -INFINITY;
    int   besti = 1 << 30;
    for (int i = lane; i < GRID_D; i += 64) {
        float v = x[i];
        if (v > bestv || (v == bestv && i < besti)) { bestv = v; besti = i; }
    }
#pragma unroll
    for (int off = 32; off > 0; off >>= 1) {
        float ov = __shfl_down(bestv, off);
        int   oi = __shfl_down(besti, off);
        if (ov > bestv || (ov == bestv && oi < besti)) { bestv = ov; besti = oi; }
    }
    if (lane == 0) {
        const int ptr = besti;
        int cells[6];
        cells[0] = 0;
        cells[1] = ptr;
        cells[2] = min(max(ptr - 19, 1), GRID_D - 1);
        cells[3] = min(max(ptr + 19, 1), GRID_D - 1);
        cells[4] = min(max(ptr - 1,  1), GRID_D - 1);
        cells[5] = min(max(ptr + 1,  1), GRID_D - 1);
        float att[6], ss = 0.f;
#pragma unroll
        for (int j = 0; j < 6; ++j) { att[j] = x[cells[j]]; ss += att[j] * att[j]; }
        const float inv = 1.f / (sqrtf(ss) + EPSV);
#pragma unroll
        for (int j = 0; j < 6; ++j) {
            qout[b * 6 + j]    = att[j] * inv;
            cellout[b * 6 + j] = cells[j];
        }
        const int a   = batch_a[b];
        const int pos = atomicAdd(&cnt[a], 1);
        rowlist[a * B + pos] = b;
    }
}

// ---------- main: 8 rows/block, 512 thr, full key range, fused finalize ----------
template <int PACKED>
__global__ __launch_bounds__(NTHR) void main_kernel(
    const float* __restrict__ batch_x,
    const float* __restrict__ keys,
    const float* __restrict__ values,
    const float* __restrict__ packed,
    const int*   __restrict__ cnt,
    const int*   __restrict__ rowlist,
    const float* __restrict__ qin,
    const int*   __restrict__ cellin,
    float* __restrict__ out_x,
    float* __restrict__ out_unc,
    float* __restrict__ out_done,
    int B)
{
    const int a     = blockIdx.y;
    const int base  = blockIdx.x * MROWS;
    const int count = cnt[a];
    if (base >= count) return;
    const int tid  = threadIdx.x;
    const int lane = tid & 63;
    const int w    = tid >> 6;

    __shared__ int   s_row[MROWS];
    __shared__ float s_q[MROWS][6];
    __shared__ int   s_cell[MROWS][6];
    __shared__ float s_red[8][64];
    __shared__ float s_redm[8][MROWS];
    __shared__ float s_tot[64];
    __shared__ float s_mx[MROWS];
    __shared__ float s_delta[MROWS][6];

    if (tid < MROWS)
        s_row[tid] = (base + tid < count) ? rowlist[a * B + base + tid] : -1;
    if (tid < MROWS * 6) {
        const int r = tid / 6, j = tid % 6;
        const int row = (base + r < count) ? rowlist[a * B + base + r] : -1;
        s_q[r][j]    = (row >= 0) ? qin[row * 6 + j]    : 0.f;
        s_cell[r][j] = (row >= 0) ? cellin[row * 6 + j] : 0;
    }
    __syncthreads();

    // wave-uniform query coefficients (SGPRs)
    float qs[MROWS][6];
#pragma unroll
    for (int r = 0; r < MROWS; ++r)
#pragma unroll
        for (int j = 0; j < 6; ++j) qs[r][j] = rfl(s_q[r][j]);

    float acc[64];
    float m[MROWS];
#pragma unroll
    for (int i = 0; i < 64; ++i) acc[i] = 0.f;
#pragma unroll
    for (int r = 0; r < MROWS; ++r) m[r] = -INFINITY;

    if (PACKED) {
        const float4* __restrict__ pk = (const float4*)packed + (size_t)a * NKEYS * 4;
        for (int n = tid; n < NKEYS; n += 2 * NTHR) {
            const int  n2 = n + NTHR;
            const bool h2 = (n2 < NKEYS);
            const float4 A0 = pk[n * 4 + 0], A1 = pk[n * 4 + 1],
                         A2 = pk[n * 4 + 2], A3 = pk[n * 4 + 3];
            float4 B0, B1, B2, B3;
            if (h2) { B0 = pk[n2 * 4 + 0]; B1 = pk[n2 * 4 + 1];
                      B2 = pk[n2 * 4 + 2]; B3 = pk[n2 * 4 + 3]; }
            {
                const float v0 = A1.z, v1 = A1.w, v2 = A2.x, v3 = A2.y,
                            v4 = A2.z, v5 = A2.w, v6 = A3.x;
#pragma unroll
                for (int r = 0; r < MROWS; ++r) {
                    const float s = qs[r][0]*A0.x + qs[r][1]*A0.y + qs[r][2]*A0.z +
                                    qs[r][3]*A0.w + qs[r][4]*A1.x + qs[r][5]*A1.y;
                    m[r] = fmaxf(m[r], s);
                    const float e = __expf(s - 1.f);   // sim<=1; softmax shift-invariant
                    acc[r*8+0] += e;
                    acc[r*8+1] += e*v0; acc[r*8+2] += e*v1; acc[r*8+3] += e*v2;
                    acc[r*8+4] += e*v3; acc[r*8+5] += e*v4; acc[r*8+6] += e*v5;
                    acc[r*8+7] += e*v6;
                }
            }
            if (h2) {
                const float v0 = B1.z, v1 = B1.w, v2 = B2.x, v3 = B2.y,
                            v4 = B2.z, v5 = B2.w, v6 = B3.x;
#pragma unroll
                for (int r = 0; r < MROWS; ++r) {
                    const float s = qs[r][0]*B0.x + qs[r][1]*B0.y + qs[r][2]*B0.z +
                                    qs[r][3]*B0.w + qs[r][4]*B1.x + qs[r][5]*B1.y;
                    m[r] = fmaxf(m[r], s);
                    const float e = __expf(s - 1.f);
                    acc[r*8+0] += e;
                    acc[r*8+1] += e*v0; acc[r*8+2] += e*v1; acc[r*8+3] += e*v2;
                    acc[r*8+4] += e*v3; acc[r*8+5] += e*v4; acc[r*8+6] += e*v5;
                    acc[r*8+7] += e*v6;
                }
            }
        }
    } else {
        const float* __restrict__ krow = keys   + (size_t)a * NKEYS * 6;
        const float* __restrict__ vrow = values + (size_t)a * NKEYS * 7;
        for (int n = tid; n < NKEYS; n += NTHR) {
            const float* kp = krow + n * 6;
            const float2 k01 = *(const float2*)(kp);
            const float2 k23 = *(const float2*)(kp + 2);
            const float2 k45 = *(const float2*)(kp + 4);
            const float nn = k01.x*k01.x + k01.y*k01.y + k23.x*k23.x +
                             k23.y*k23.y + k45.x*k45.x + k45.y*k45.y;
            const float invn = 1.f / (sqrtf(nn) + EPSV);
            const float* vp = vrow + n * 7;
            const float v0 = vp[0], v1 = vp[1], v2 = vp[2], v3 = vp[3],
                        v4 = vp[4], v5 = vp[5], v6 = vp[6];
#pragma unroll
            for (int r = 0; r < MROWS; ++r) {
                const float dot = qs[r][0]*k01.x + qs[r][1]*k01.y + qs[r][2]*k23.x +
                                  qs[r][3]*k23.y + qs[r][4]*k45.x + qs[r][5]*k45.y;
                const float s = dot * invn;
                m[r] = fmaxf(m[r], s);
                const float e = __expf(s - 1.f);
                acc[r*8+0] += e;
                acc[r*8+1] += e*v0; acc[r*8+2] += e*v1; acc[r*8+3] += e*v2;
                acc[r*8+4] += e*v3; acc[r*8+5] += e*v4; acc[r*8+6] += e*v5;
                acc[r*8+7] += e*v6;
            }
        }
    }

    // ---- in-wave log reduce-scatter: lane l ends owning flat value l ----
#pragma unroll
    for (int bit = 32; bit >= 1; bit >>= 1) {
        const bool up = (lane & bit) != 0;
#pragma unroll
        for (int i = 0; i < bit; ++i) {
            const float send = up ? acc[i] : acc[i + bit];
            const float recv = __shfl_xor(send, bit);
            acc[i] = (up ? acc[i + bit] : acc[i]) + recv;
        }
    }
    // max: 8 values -> scatter over lane bits {32,16,8}, then finish bits {4,2,1}
#pragma unroll
    for (int bit = 32; bit >= 8; bit >>= 1) {
        const int  c  = bit >> 3;
        const bool up = (lane & bit) != 0;
#pragma unroll
        for (int i = 0; i < c; ++i) {
            const float send = up ? m[i] : m[i + c];
            const float recv = __shfl_xor(send, bit);
            m[i] = fmaxf(up ? m[i + c] : m[i], recv);
        }
    }
    float m0 = m[0];
#pragma unroll
    for (int bit = 4; bit >= 1; bit >>= 1) m0 = fmaxf(m0, __shfl_xor(m0, bit));

    s_red[w][lane] = acc[0];
    if ((lane & 7) == 0) s_redm[w][lane >> 3] = m0;
    __syncthreads();

    // ---- cross-wave combine ----
    if (tid < 64) {
        float t = 0.f;
#pragma unroll
        for (int ww = 0; ww < 8; ++ww) t += s_red[ww][tid];
        s_tot[tid] = t;
    } else if (tid < 64 + MROWS) {
        const int r = tid - 64;
        float mm = s_redm[0][r];
#pragma unroll
        for (int ww = 1; ww < 8; ++ww) mm = fmaxf(mm, s_redm[ww][r]);
        s_mx[r] = mm;
    }
    __syncthreads();

    if (tid < MROWS) {
        const int r = tid, row = s_row[r];
        if (row >= 0) {
            const float inv = 1.f / s_tot[r * 8];
#pragma unroll
            for (int j = 0; j < 6; ++j) s_delta[r][j] = s_tot[r * 8 + 1 + j] * inv;
            out_done[row] = s_tot[r * 8 + 7] * inv;
            out_unc[row]  = -s_mx[r];
        }
    }
    __syncthreads();

    // ---- scatter deltas (ascending j -> last write wins) + copy rows ----
    for (int f = tid; f < MROWS * GRID_D; f += NTHR) {
        const int r = f / GRID_D;
        const int c = f - r * GRID_D;
        const int row = s_row[r];
        if (row < 0) continue;
        float add = 0.f;
#pragma unroll
        for (int j = 0; j < 6; ++j)
            if (s_cell[r][j] == c) add = s_delta[r][j];
        out_x[(size_t)row * GRID_D + c] = batch_x[(size_t)row * GRID_D + c] + add;
    }
}

extern "C" void kernel_launch(void* const* d_in, const int* in_sizes, int n_in,
                              void* d_out, int out_size, void* d_ws, size_t ws_size,
                              hipStream_t stream) {
    const float* batch_x = (const float*)d_in[0];
    const int*   batch_a = (const int*)d_in[1];
    const float* keys    = (const float*)d_in[2];
    const float* values  = (const float*)d_in[3];
    const int B = in_sizes[1];                 // 4096

    float* out      = (float*)d_out;
    float* out_x    = out;
    float* out_unc  = out + (size_t)B * GRID_D;
    float* out_done = out_unc + B;

    // workspace layout
    int*   cnt     = (int*)d_ws;                        // 4 ints
    int*   rowlist = cnt + 4;                           // 3*B ints
    float* qbuf    = (float*)(rowlist + 3 * B);         // B*6 floats
    int*   cellbuf = (int*)(qbuf + (size_t)B * 6);      // B*6 ints
    float* packed  = (float*)(cellbuf + (size_t)B * 6); // 3*NKEYS*16 floats

    const size_t fixed_bytes = ((size_t)4 + 3 * B + 6 * B + 6 * B) * 4;
    const size_t pack_bytes  = (size_t)3 * NKEYS * 16 * 4;
    const int do_pack = (ws_size >= fixed_bytes + pack_bytes) ? 1 : 0;

    hipMemsetAsync(cnt, 0, 4 * sizeof(int), stream);

    const int prep_blocks = (B + 3) / 4;
    const int pack_blocks = do_pack ? (3 * NKEYS + 255) / 256 : 0;
    prep_pack_kernel<<<dim3(prep_blocks + pack_blocks), 256, 0, stream>>>(
        batch_x, batch_a, keys, values, cnt, rowlist, qbuf, cellbuf,
        packed, B, prep_blocks, do_pack);

    const dim3 grid((B + MROWS - 1) / MROWS, 3);
    if (do_pack)
        main_kernel<1><<<grid, NTHR, 0, stream>>>(
            batch_x, keys, values, packed, cnt, rowlist, qbuf, cellbuf,
            out_x, out_unc, out_done, B);
    else
        main_kernel<0><<<grid, NTHR, 0, stream>>>(
            batch_x, keys, values, packed, cnt, rowlist, qbuf, cellbuf,
            out_x, out_unc, out_done, B);
}